// Round 12
// baseline (941.079 us; speedup 1.0000x reference)
//
#include <hip/hip_runtime.h>
#include <hip/hip_bf16.h>

#define N_NODES  100000
#define N_EDGES  1600000
#define N_GRAPHS 256
#define DCH      128
#define DOUT     64
#define NB       391      // buckets = ceil(100000/256)
#define PADB     512
#define SLACK    4608     // per-bucket region capacity (mean 4096 + 8 sigma)
#define CHUNK    4096     // edges per binA block
#define PCH      64       // nodes per pool block
#define SLCH     16       // channels per agg slice (128/8 XCDs)

typedef short v8s __attribute__((ext_vector_type(8)));
typedef float v4f __attribute__((ext_vector_type(4)));

static __device__ __forceinline__ float bf2f(unsigned short u) {
    unsigned int x = ((unsigned int)u) << 16;
    return __builtin_bit_cast(float, x);
}
static __device__ __forceinline__ float lobf(unsigned int v) {
    return __builtin_bit_cast(float, v << 16);
}
static __device__ __forceinline__ float hibf(unsigned int v) {
    return __builtin_bit_cast(float, v & 0xffff0000u);
}
static __device__ __forceinline__ unsigned short f2bf(float f) {
    unsigned int x = __builtin_bit_cast(unsigned int, f);
    unsigned int r = (x + 0x7fffu + ((x >> 16) & 1u)) >> 16;
    return (unsigned short)r;
}
static __device__ __forceinline__ int clampi(int v, int lo, int hi) {
    return v < lo ? lo : (v > hi ? hi : v);
}

// ---------------- fp32 -> bf16 feature conversion ----------------
__global__ void cvt_kernel(const float* __restrict__ in, unsigned short* __restrict__ out) {
    size_t i = ((size_t)blockIdx.x * blockDim.x + threadIdx.x) * 4;
    if (i + 3 < (size_t)N_NODES * DCH) {
        float4 f = *reinterpret_cast<const float4*>(in + i);
        uint2 o;
        o.x = ((unsigned)f2bf(f.y) << 16) | (unsigned)f2bf(f.x);
        o.y = ((unsigned)f2bf(f.w) << 16) | (unsigned)f2bf(f.z);
        *reinterpret_cast<uint2*>(out + i) = o;
    }
}

// ---------------- edge binning pass A: partition edges into dst>>8 buckets ----------------
// gcur must be zero-initialized; bucket b's region base is b*SLACK.
__global__ void __launch_bounds__(256) binA_kernel(const int* __restrict__ src, const int* __restrict__ dst,
                                                   int* __restrict__ gcur, uint2* __restrict__ region) {
    __shared__ uint2 stage[CHUNK];          // 32 KB
    __shared__ int hcnt[PADB], hcnt2[PADB], hoff[PADB], garr[PADB];
    __shared__ int s2[256];
    int tid = threadIdx.x;
    int e0  = blockIdx.x * CHUNK;
    int nedge = N_EDGES - e0; if (nedge > CHUNK) nedge = CHUNK;

    for (int b = tid; b < PADB; b += 256) { hcnt[b] = 0; hcnt2[b] = 0; }
    __syncthreads();

    // phase 1: read edges into registers, LDS bucket histogram
    int es[16], ed[16];
    #pragma unroll
    for (int j = 0; j < 16; j++) {
        int e = e0 + j * 256 + tid;
        if (e < N_EDGES) {
            es[j] = clampi(src[e], 0, N_NODES - 1);
            ed[j] = clampi(dst[e], 0, N_NODES - 1);
            atomicAdd(&hcnt[ed[j] >> 8], 1);
        } else { es[j] = -1; ed[j] = 0; }
    }
    __syncthreads();

    // phase 2a: exclusive scan of hcnt[512] -> hoff
    int v0 = hcnt[2 * tid], v1 = hcnt[2 * tid + 1];
    s2[tid] = v0 + v1; __syncthreads();
    for (int off = 1; off < 256; off <<= 1) {
        int x = (tid >= off) ? s2[tid - off] : 0;
        __syncthreads();
        s2[tid] += x;
        __syncthreads();
    }
    int excl = s2[tid] - (v0 + v1);
    hoff[2 * tid] = excl; hoff[2 * tid + 1] = excl + v0;
    __syncthreads();

    // phase 2b: reserve global bucket space (gcur holds counts; base b*SLACK added here)
    for (int b = tid; b < NB; b += 256) {
        int c = hcnt[b];
        garr[b] = b * SLACK + ((c > 0) ? atomicAdd(&gcur[b], c) : 0);
    }
    __syncthreads();

    // phase 3: place edges into stage, bucket-contiguous
    #pragma unroll
    for (int j = 0; j < 16; j++) {
        if (es[j] >= 0) {
            int b = ed[j] >> 8;
            int pos = atomicAdd(&hcnt2[b], 1) + hoff[b];
            stage[pos] = (uint2){(unsigned)es[j], (unsigned)ed[j]};
        }
    }
    __syncthreads();

    // phase 4: coalesced-ish write of bucket runs to global region
    for (int i = tid; i < nedge; i += 256) {
        uint2 en = stage[i];
        int b = (int)(en.y >> 8);
        int gpos = garr[b] + (i - hoff[b]);
        if (gpos < (b + 1) * SLACK) region[gpos] = en;   // overflow guard (prob ~0)
    }
}

// ---------------- binFinish: per-bucket degree + rowptr + csr scatter (fused) ----------------
__global__ void __launch_bounds__(256) binFinish_kernel(const uint2* __restrict__ region, const int* __restrict__ gcur,
                                                        int* __restrict__ rowptr, int* __restrict__ csr) {
    __shared__ int h[256], sc[256], cur[256], s2[256], hoff[PADB];
    int b = blockIdx.x, tid = threadIdx.x;
    // 1. global bucket prefix (all blocks redundantly; gcur entries >= NB are 0)
    int c0 = gcur[2 * tid];     if (c0 > SLACK) c0 = SLACK;
    int c1 = gcur[2 * tid + 1]; if (c1 > SLACK) c1 = SLACK;
    s2[tid] = c0 + c1;
    h[tid] = 0;
    __syncthreads();
    for (int off = 1; off < 256; off <<= 1) {
        int x = (tid >= off) ? s2[tid - off] : 0;
        __syncthreads();
        s2[tid] += x;
        __syncthreads();
    }
    int excl = s2[tid] - (c0 + c1);
    hoff[2 * tid] = excl; hoff[2 * tid + 1] = excl + c0;
    __syncthreads();
    if (b == 0 && tid == 255) rowptr[N_NODES] = hoff[511];  // buckets NB..510 are 0-size
    int base = hoff[b];
    int size = gcur[b]; if (size > SLACK) size = SLACK;
    int node0 = b * 256;
    // 2. degree histogram
    for (int j = tid; j < size; j += 256) {
        unsigned loc = region[b * SLACK + j].y - (unsigned)node0;
        if (loc < 256u) atomicAdd(&h[loc], 1);
    }
    __syncthreads();
    // 3. local scan -> rowptr + cursors
    int v = h[tid]; sc[tid] = v; __syncthreads();
    for (int off = 1; off < 256; off <<= 1) {
        int x = (tid >= off) ? sc[tid - off] : 0;
        __syncthreads();
        sc[tid] += x;
        __syncthreads();
    }
    int myptr = base + sc[tid] - v;
    int node = node0 + tid;
    if (node < N_NODES) rowptr[node] = myptr;
    cur[tid] = myptr;
    __syncthreads();
    // 4. scatter into csr
    for (int j = tid; j < size; j += 256) {
        uint2 en = region[b * SLACK + j];
        unsigned loc = en.y - (unsigned)node0;
        if (loc < 256u) {
            int p = atomicAdd(&cur[loc], 1);
            if (p >= 0 && p < N_EDGES) csr[p] = (int)en.x;
        }
    }
}

// ---------------- weight fragment pre-swizzle (fp32 -> bf16) ----------------
// B [256x128] = [Wrel; Wroot]; mfma_f32_16x16x32_bf16 B-layout:
// lane holds B[k = kt*32 + (lane>>4)*8 + j][n = nt*16 + (lane&15)]
__global__ void wfrag_kernel(const float* __restrict__ W1rel, const float* __restrict__ W1root,
                             const float* __restrict__ W2rel, const float* __restrict__ W2root,
                             const float* __restrict__ W3rel, const float* __restrict__ W3root,
                             unsigned short* __restrict__ frag) {
    int gid = blockIdx.x * blockDim.x + threadIdx.x;
    if (gid >= 3 * 8 * 8 * 64) return;
    int lane = gid & 63;
    int nt   = (gid >> 6) & 7;
    int kt   = (gid >> 9) & 7;
    int L    = gid >> 12;
    const float* rel  = (L == 0) ? W1rel  : (L == 1) ? W2rel  : W3rel;
    const float* root = (L == 0) ? W1root : (L == 1) ? W2root : W3root;
    int n  = nt * 16 + (lane & 15);
    int k0 = kt * 32 + (lane >> 4) * 8;
    unsigned short o[8];
    #pragma unroll
    for (int j = 0; j < 8; j++) {
        int k = k0 + j;
        float w = (k < 128) ? rel[k * 128 + n] : root[(k - 128) * 128 + n];
        o[j] = f2bf(w);
    }
    uint4 u;
    u.x = (unsigned)o[0] | ((unsigned)o[1] << 16);
    u.y = (unsigned)o[2] | ((unsigned)o[3] << 16);
    u.z = (unsigned)o[4] | ((unsigned)o[5] << 16);
    u.w = (unsigned)o[6] | ((unsigned)o[7] << 16);
    *reinterpret_cast<uint4*>(frag + (size_t)gid * 8) = u;
}

// ---------------- channel-sliced aggregate: aggS[slice][node][16ch] ----------------
// block b: slice = b&7 (XCD-pinned under round-robin dispatch), nodes (b>>3)*4..+3.
// Per-XCD gather working set = 100k * 32 B = 3.2 MB -> L2-resident.
// Wave = 1 node: 64 lanes = 16 edge slots x 4 channel-quads (uint2 = 4 ch each).
__global__ void __launch_bounds__(256) agg_kernel(const unsigned short* __restrict__ hin,
                                                  const int* __restrict__ rowptr, const int* __restrict__ csr,
                                                  unsigned short* __restrict__ aggS) {
    int slice = blockIdx.x & 7;
    int group = blockIdx.x >> 3;
    int wave  = threadIdx.x >> 6;
    int lane  = threadIdx.x & 63;
    int node  = group * 4 + wave;
    if (node >= N_NODES) return;
    int r0 = rowptr[node], r1 = rowptr[node + 1];
    int eg = lane >> 2;      // edge slot 0..15
    int q  = lane & 3;       // channel quad within slice
    const unsigned short* colbase = hin + slice * SLCH + q * 4;
    float a0 = 0.f, a1 = 0.f, a2 = 0.f, a3 = 0.f;
    for (int c = r0; c < r1; c += 16) {
        int ii = c + eg; if (ii > r1 - 1) ii = r1 - 1;
        int s = csr[ii];                                  // coalesced, 4-way replicated
        uint2 v = *reinterpret_cast<const uint2*>(colbase + (size_t)s * DCH);
        float w = (c + eg < r1) ? 1.0f : 0.0f;
        a0 = fmaf(w, lobf(v.x), a0); a1 = fmaf(w, hibf(v.x), a1);
        a2 = fmaf(w, lobf(v.y), a2); a3 = fmaf(w, hibf(v.y), a3);
    }
    // reduce across the 16 edge slots (lanes differing in bits 2..5)
    #pragma unroll
    for (int off = 4; off < 64; off <<= 1) {
        a0 += __shfl_xor(a0, off); a1 += __shfl_xor(a1, off);
        a2 += __shfl_xor(a2, off); a3 += __shfl_xor(a3, off);
    }
    int deg = r1 - r0;
    float inv = 1.0f / (float)(deg > 1 ? deg : 1);
    if (lane < 4) {
        uint2 o;
        o.x = ((unsigned)f2bf(a1 * inv) << 16) | (unsigned)f2bf(a0 * inv);
        o.y = ((unsigned)f2bf(a3 * inv) << 16) | (unsigned)f2bf(a2 * inv);
        *reinterpret_cast<uint2*>(aggS + ((size_t)slice * N_NODES + node) * SLCH + q * 4) = o;
    }
}

// ---------------- fused GEMM: hout = act( [aggS|root] @ [Wrel;Wroot] + b ) ----------------
// A-agg read slice-major; M=32 rows/wave. hout may alias root (in-place): each
// wave reads only its own 32 root rows before its stores -> no __restrict__.
__global__ void gemm_kernel(const unsigned short* __restrict__ aggS, const unsigned short* root,
                            const unsigned short* __restrict__ frag, const float* __restrict__ bias,
                            unsigned short* hout, int relu) {
    int wave = threadIdx.x >> 6;
    int lane = threadIdx.x & 63;
    int quad = lane >> 4;
    int ml   = lane & 15;
    int base = blockIdx.x * 128 + wave * 32;
    int r0 = clampi(base + ml, 0, N_NODES - 1);
    int r1 = clampi(base + 16 + ml, 0, N_NODES - 1);
    v4f acc[2][8];
    #pragma unroll
    for (int h = 0; h < 2; h++)
        #pragma unroll
        for (int nt = 0; nt < 8; nt++) acc[h][nt] = (v4f){0.f, 0.f, 0.f, 0.f};
    #pragma unroll
    for (int kt = 0; kt < 8; kt++) {
        int ak = (kt & 3) * 32 + quad * 8;
        v8s a0, a1;
        if (kt < 4) {
            const unsigned short* sp = aggS + (size_t)(ak >> 4) * N_NODES * SLCH + (ak & 15);
            a0 = *reinterpret_cast<const v8s*>(sp + (size_t)r0 * SLCH);
            a1 = *reinterpret_cast<const v8s*>(sp + (size_t)r1 * SLCH);
        } else {
            a0 = *reinterpret_cast<const v8s*>(root + (size_t)r0 * DCH + ak);
            a1 = *reinterpret_cast<const v8s*>(root + (size_t)r1 * DCH + ak);
        }
        #pragma unroll
        for (int nt = 0; nt < 8; nt++) {
            v8s b = *reinterpret_cast<const v8s*>(frag + (((size_t)(kt * 8 + nt)) * 64 + lane) * 8);
            acc[0][nt] = __builtin_amdgcn_mfma_f32_16x16x32_bf16(a0, b, acc[0][nt], 0, 0, 0);
            acc[1][nt] = __builtin_amdgcn_mfma_f32_16x16x32_bf16(a1, b, acc[1][nt], 0, 0, 0);
        }
    }
    #pragma unroll
    for (int h = 0; h < 2; h++) {
        int mbase = base + h * 16 + quad * 4;
        #pragma unroll
        for (int nt = 0; nt < 8; nt++) {
            int n = nt * 16 + ml;
            float bv = bias[n];
            #pragma unroll
            for (int r = 0; r < 4; r++) {
                int row = mbase + r;
                if (row < N_NODES) {
                    float v = acc[h][nt][r] + bv;
                    if (relu) v = fmaxf(v, 0.f);
                    hout[(size_t)row * DCH + n] = f2bf(v);
                }
            }
        }
    }
}

// ---------------- pooling stage 1: segmented sum into psum (batch sorted) ----------------
__global__ void __launch_bounds__(128) pool_kernel(const unsigned short* __restrict__ h,
                                                   const int* __restrict__ batch,
                                                   float* __restrict__ psum) {
    int c  = threadIdx.x; // 0..127
    int n0 = blockIdx.x * PCH;
    int n1 = n0 + PCH < N_NODES ? n0 + PCH : N_NODES;
    if (n0 >= n1) return;
    int cur = clampi(batch[n0], 0, N_GRAPHS - 1);
    float acc = 0.f;
    for (int n = n0; n < n1; n++) {
        int g = clampi(batch[n], 0, N_GRAPHS - 1);
        if (g != cur) {
            atomicAdd(&psum[cur * DCH + c], acc);
            acc = 0.f; cur = g;
        }
        acc += bf2f(h[(size_t)n * DCH + c]);
    }
    atomicAdd(&psum[cur * DCH + c], acc);
}

// ---------------- pooling stage 2: out[g] = (psum[g]/cnt_g) @ Wl + bl ----------------
static __device__ __forceinline__ int lowerb(const int* __restrict__ a, int n, int key) {
    int lo = 0, hi = n;
    while (lo < hi) { int mid = (lo + hi) >> 1; if (a[mid] < key) lo = mid + 1; else hi = mid; }
    return lo;
}

__global__ void __launch_bounds__(64) final_kernel(const float* __restrict__ psum,
                                                   const int* __restrict__ batch,
                                                   const float* __restrict__ Wl, const float* __restrict__ bl,
                                                   float* __restrict__ out) {
    __shared__ float ps[DCH];
    __shared__ int bounds[2];
    int g = blockIdx.x, tid = threadIdx.x;
    if (tid == 0) {
        bounds[0] = lowerb(batch, N_NODES, g);
        bounds[1] = lowerb(batch, N_NODES, g + 1);
    }
    __syncthreads();
    int cnt = bounds[1] - bounds[0];
    float inv = 1.0f / (float)(cnt > 1 ? cnt : 1);
    ps[tid] = psum[g * DCH + tid] * inv;
    ps[tid + 64] = psum[g * DCH + tid + 64] * inv;
    __syncthreads();
    float o = 0.f;
    #pragma unroll 4
    for (int c = 0; c < DCH; c++) o += ps[c] * Wl[c * DOUT + tid];
    out[g * DOUT + tid] = o + bl[tid];
}

extern "C" void kernel_launch(void* const* d_in, const int* in_sizes, int n_in,
                              void* d_out, int out_size, void* d_ws, size_t ws_size,
                              hipStream_t stream) {
    const float* x     = (const float*)d_in[0];
    const int*   edge  = (const int*)d_in[1];
    const int*   src   = edge;
    const int*   dst   = edge + N_EDGES;
    const int*   batch = (const int*)d_in[2];
    const float* W1rel  = (const float*)d_in[3];
    const float* b1     = (const float*)d_in[4];
    const float* W1root = (const float*)d_in[5];
    const float* W2rel  = (const float*)d_in[6];
    const float* b2     = (const float*)d_in[7];
    const float* W2root = (const float*)d_in[8];
    const float* W3rel  = (const float*)d_in[9];
    const float* b3     = (const float*)d_in[10];
    const float* W3root = (const float*)d_in[11];
    const float* Wl     = (const float*)d_in[12];
    const float* bl     = (const float*)d_in[13];
    float* out = (float*)d_out;

    char* ws = (char*)d_ws;
    size_t off = 0;
    auto carve = [&](size_t bytes) -> void* {
        void* p = ws + off;
        off += (bytes + 255) & ~(size_t)255;
        return p;
    };
    // ~58 MiB total; bucket region reuses Bagg (free during CSR build)
    int*            rowptr  = (int*)carve((size_t)(N_NODES + 1) * 4);
    int*            csr     = (int*)carve((size_t)N_EDGES * 4);
    int*            gcur    = (int*)carve((size_t)PADB * 4 + (size_t)N_GRAPHS * DCH * 4); // gcur + psum, one memset
    float*          psum    = (float*)(gcur + PADB);
    unsigned short* frag    = (unsigned short*)carve((size_t)3 * 8 * 8 * 64 * 8 * 2);
    unsigned short* B1      = (unsigned short*)carve((size_t)N_NODES * DCH * 2);   // row-major features (in-place)
    unsigned short* Bagg    = (unsigned short*)carve((size_t)N_NODES * DCH * 2);   // slice-major agg scratch
    uint2*          region  = (uint2*)Bagg;   // 391*4608*8 = 14.4 MB <= 25.6 MB

    hipMemsetAsync(gcur, 0, (size_t)PADB * 4 + (size_t)N_GRAPHS * DCH * 4, stream);

    // CSR build: binA -> binFinish
    binA_kernel<<<(N_EDGES + CHUNK - 1) / CHUNK, 256, 0, stream>>>(src, dst, gcur, region);
    binFinish_kernel<<<NB, 256, 0, stream>>>(region, gcur, rowptr, csr);
    // features + weights
    cvt_kernel<<<(N_NODES * DCH / 4 + 255) / 256, 256, 0, stream>>>(x, B1);
    wfrag_kernel<<<(3 * 8 * 8 * 64 + 255) / 256, 256, 0, stream>>>(W1rel, W1root, W2rel, W2root, W3rel, W3root, frag);

    const int aggGrid  = 8 * ((N_NODES + 3) / 4);
    const int gemmGrid = (N_NODES + 127) / 128;

    // layer 1: agg(B1) -> Bagg; gemm [Bagg|B1] -> B1 (relu, in-place)
    agg_kernel<<<aggGrid, 256, 0, stream>>>(B1, rowptr, csr, Bagg);
    gemm_kernel<<<gemmGrid, 256, 0, stream>>>(Bagg, B1, frag, b1, B1, 1);
    // layer 2
    agg_kernel<<<aggGrid, 256, 0, stream>>>(B1, rowptr, csr, Bagg);
    gemm_kernel<<<gemmGrid, 256, 0, stream>>>(Bagg, B1, frag + 32768, b2, B1, 1);
    // layer 3 (no relu)
    agg_kernel<<<aggGrid, 256, 0, stream>>>(B1, rowptr, csr, Bagg);
    gemm_kernel<<<gemmGrid, 256, 0, stream>>>(Bagg, B1, frag + 65536, b3, B1, 0);

    // pooling: wide segmented sum, then per-graph matvec
    pool_kernel<<<(N_NODES + PCH - 1) / PCH, 128, 0, stream>>>(B1, batch, psum);
    final_kernel<<<N_GRAPHS, 64, 0, stream>>>(psum, batch, Wl, bl, out);
}

// Round 13
// 447.741 us; speedup vs baseline: 2.1018x; 2.1018x over previous
//
#include <hip/hip_runtime.h>
#include <hip/hip_bf16.h>

#define N_NODES  100000
#define N_EDGES  1600000
#define N_GRAPHS 256
#define DCH      128
#define DOUT     64
#define NB       391      // buckets = ceil(100000/256)
#define PADB     512
#define SLACK    4608     // per-bucket region capacity (mean 4096 + 8 sigma)
#define CHUNK    4096     // edges per binA block
#define PCH      64       // nodes per pool block

typedef short v8s __attribute__((ext_vector_type(8)));
typedef float v4f __attribute__((ext_vector_type(4)));

static __device__ __forceinline__ float bf2f(unsigned short u) {
    unsigned int x = ((unsigned int)u) << 16;
    return __builtin_bit_cast(float, x);
}
static __device__ __forceinline__ unsigned short f2bf(float f) {
    unsigned int x = __builtin_bit_cast(unsigned int, f);
    unsigned int r = (x + 0x7fffu + ((x >> 16) & 1u)) >> 16;
    return (unsigned short)r;
}
static __device__ __forceinline__ int clampi(int v, int lo, int hi) {
    return v < lo ? lo : (v > hi ? hi : v);
}

// ---------------- fp32 -> bf16 feature conversion ----------------
__global__ void cvt_kernel(const float* __restrict__ in, unsigned short* __restrict__ out) {
    size_t i = ((size_t)blockIdx.x * blockDim.x + threadIdx.x) * 4;
    if (i + 3 < (size_t)N_NODES * DCH) {
        float4 f = *reinterpret_cast<const float4*>(in + i);
        uint2 o;
        o.x = ((unsigned)f2bf(f.y) << 16) | (unsigned)f2bf(f.x);
        o.y = ((unsigned)f2bf(f.w) << 16) | (unsigned)f2bf(f.z);
        *reinterpret_cast<uint2*>(out + i) = o;
    }
}

// ---------------- edge binning pass A: partition edges into dst>>8 buckets ----------------
// gcur must be zero-initialized; bucket b's region base is b*SLACK.
__global__ void __launch_bounds__(256) binA_kernel(const int* __restrict__ src, const int* __restrict__ dst,
                                                   int* __restrict__ gcur, uint2* __restrict__ region) {
    __shared__ uint2 stage[CHUNK];          // 32 KB
    __shared__ int hcnt[PADB], hcnt2[PADB], hoff[PADB], garr[PADB];
    __shared__ int s2[256];
    int tid = threadIdx.x;
    int e0  = blockIdx.x * CHUNK;
    int nedge = N_EDGES - e0; if (nedge > CHUNK) nedge = CHUNK;

    for (int b = tid; b < PADB; b += 256) { hcnt[b] = 0; hcnt2[b] = 0; }
    __syncthreads();

    // phase 1: read edges into registers, LDS bucket histogram
    int es[16], ed[16];
    #pragma unroll
    for (int j = 0; j < 16; j++) {
        int e = e0 + j * 256 + tid;
        if (e < N_EDGES) {
            es[j] = clampi(src[e], 0, N_NODES - 1);
            ed[j] = clampi(dst[e], 0, N_NODES - 1);
            atomicAdd(&hcnt[ed[j] >> 8], 1);
        } else { es[j] = -1; ed[j] = 0; }
    }
    __syncthreads();

    // phase 2a: exclusive scan of hcnt[512] -> hoff
    int v0 = hcnt[2 * tid], v1 = hcnt[2 * tid + 1];
    s2[tid] = v0 + v1; __syncthreads();
    for (int off = 1; off < 256; off <<= 1) {
        int x = (tid >= off) ? s2[tid - off] : 0;
        __syncthreads();
        s2[tid] += x;
        __syncthreads();
    }
    int excl = s2[tid] - (v0 + v1);
    hoff[2 * tid] = excl; hoff[2 * tid + 1] = excl + v0;
    __syncthreads();

    // phase 2b: reserve global bucket space (gcur holds counts; base b*SLACK added here)
    for (int b = tid; b < NB; b += 256) {
        int c = hcnt[b];
        garr[b] = b * SLACK + ((c > 0) ? atomicAdd(&gcur[b], c) : 0);
    }
    __syncthreads();

    // phase 3: place edges into stage, bucket-contiguous
    #pragma unroll
    for (int j = 0; j < 16; j++) {
        if (es[j] >= 0) {
            int b = ed[j] >> 8;
            int pos = atomicAdd(&hcnt2[b], 1) + hoff[b];
            stage[pos] = (uint2){(unsigned)es[j], (unsigned)ed[j]};
        }
    }
    __syncthreads();

    // phase 4: coalesced-ish write of bucket runs to global region
    for (int i = tid; i < nedge; i += 256) {
        uint2 en = stage[i];
        int b = (int)(en.y >> 8);
        int gpos = garr[b] + (i - hoff[b]);
        if (gpos < (b + 1) * SLACK) region[gpos] = en;   // overflow guard (prob ~0)
    }
}

// ---------------- binFinish: per-bucket degree + rowptr + csr scatter (fused) ----------------
__global__ void __launch_bounds__(256) binFinish_kernel(const uint2* __restrict__ region, const int* __restrict__ gcur,
                                                        int* __restrict__ rowptr, int* __restrict__ csr) {
    __shared__ int h[256], sc[256], cur[256], s2[256], hoff[PADB];
    int b = blockIdx.x, tid = threadIdx.x;
    // 1. global bucket prefix (all blocks redundantly; gcur entries >= NB are 0)
    int c0 = gcur[2 * tid];     if (c0 > SLACK) c0 = SLACK;
    int c1 = gcur[2 * tid + 1]; if (c1 > SLACK) c1 = SLACK;
    s2[tid] = c0 + c1;
    h[tid] = 0;
    __syncthreads();
    for (int off = 1; off < 256; off <<= 1) {
        int x = (tid >= off) ? s2[tid - off] : 0;
        __syncthreads();
        s2[tid] += x;
        __syncthreads();
    }
    int excl = s2[tid] - (c0 + c1);
    hoff[2 * tid] = excl; hoff[2 * tid + 1] = excl + c0;
    __syncthreads();
    if (b == 0 && tid == 255) rowptr[N_NODES] = hoff[511];  // buckets NB..510 are 0-size
    int base = hoff[b];
    int size = gcur[b]; if (size > SLACK) size = SLACK;
    int node0 = b * 256;
    // 2. degree histogram
    for (int j = tid; j < size; j += 256) {
        unsigned loc = region[b * SLACK + j].y - (unsigned)node0;
        if (loc < 256u) atomicAdd(&h[loc], 1);
    }
    __syncthreads();
    // 3. local scan -> rowptr + cursors
    int v = h[tid]; sc[tid] = v; __syncthreads();
    for (int off = 1; off < 256; off <<= 1) {
        int x = (tid >= off) ? sc[tid - off] : 0;
        __syncthreads();
        sc[tid] += x;
        __syncthreads();
    }
    int myptr = base + sc[tid] - v;
    int node = node0 + tid;
    if (node < N_NODES) rowptr[node] = myptr;
    cur[tid] = myptr;
    __syncthreads();
    // 4. scatter into csr
    for (int j = tid; j < size; j += 256) {
        uint2 en = region[b * SLACK + j];
        unsigned loc = en.y - (unsigned)node0;
        if (loc < 256u) {
            int p = atomicAdd(&cur[loc], 1);
            if (p >= 0 && p < N_EDGES) csr[p] = (int)en.x;
        }
    }
}

// ---------------- weight fragment pre-swizzle (fp32 -> bf16) ----------------
// B [256x128] = [Wrel; Wroot]; mfma_f32_16x16x32_bf16 B-layout:
// lane holds B[k = kt*32 + (lane>>4)*8 + j][n = nt*16 + (lane&15)]
__global__ void wfrag_kernel(const float* __restrict__ W1rel, const float* __restrict__ W1root,
                             const float* __restrict__ W2rel, const float* __restrict__ W2root,
                             const float* __restrict__ W3rel, const float* __restrict__ W3root,
                             unsigned short* __restrict__ frag) {
    int gid = blockIdx.x * blockDim.x + threadIdx.x;
    if (gid >= 3 * 8 * 8 * 64) return;
    int lane = gid & 63;
    int nt   = (gid >> 6) & 7;
    int kt   = (gid >> 9) & 7;
    int L    = gid >> 12;
    const float* rel  = (L == 0) ? W1rel  : (L == 1) ? W2rel  : W3rel;
    const float* root = (L == 0) ? W1root : (L == 1) ? W2root : W3root;
    int n  = nt * 16 + (lane & 15);
    int k0 = kt * 32 + (lane >> 4) * 8;
    unsigned short o[8];
    #pragma unroll
    for (int j = 0; j < 8; j++) {
        int k = k0 + j;
        float w = (k < 128) ? rel[k * 128 + n] : root[(k - 128) * 128 + n];
        o[j] = f2bf(w);
    }
    uint4 u;
    u.x = (unsigned)o[0] | ((unsigned)o[1] << 16);
    u.y = (unsigned)o[2] | ((unsigned)o[3] << 16);
    u.z = (unsigned)o[4] | ((unsigned)o[5] << 16);
    u.w = (unsigned)o[6] | ((unsigned)o[7] << 16);
    *reinterpret_cast<uint4*>(frag + (size_t)gid * 8) = u;
}

// ---------------- aggregate (bf16): agg[i] = mean_{e: dst=i} h[src_e] ----------------
// wave per node; 16-wide index broadcast + 16 unconditional in-flight gathers.
// (confirmed floor: 62.7 us / FETCH 178 MB / ~3.3 TB/s effective — rounds 6,10,11)
__global__ void agg_kernel(const unsigned short* __restrict__ hin, const int* __restrict__ rowptr,
                           const int* __restrict__ csr, unsigned short* __restrict__ agg) {
    int wave = threadIdx.x >> 6;
    int lane = threadIdx.x & 63;
    int node = blockIdx.x * 4 + wave;
    if (node >= N_NODES) return;
    int r0 = rowptr[node], r1 = rowptr[node + 1];
    int l16 = lane & 15;
    float a0 = 0.f, a1 = 0.f;
    for (int c = r0; c < r1; c += 16) {
        int m = r1 - c; if (m > 16) m = 16;          // wave-uniform
        int idx = csr[c + (l16 < m ? l16 : 0)];      // one coalesced 16-lane load
        #pragma unroll
        for (int j = 0; j < 16; j++) {
            int s = __shfl(idx, j);                   // broadcast lane j's index
            unsigned int v = *reinterpret_cast<const unsigned int*>(hin + (size_t)s * DCH + lane * 2);
            float w = (j < m) ? 1.0f : 0.0f;          // padded gathers weighted 0
            a0 = fmaf(w, bf2f((unsigned short)(v & 0xffffu)), a0);
            a1 = fmaf(w, bf2f((unsigned short)(v >> 16)), a1);
        }
    }
    int deg = r1 - r0;
    float inv = 1.0f / (float)(deg > 1 ? deg : 1);
    a0 *= inv; a1 *= inv;
    unsigned int o = ((unsigned int)f2bf(a1) << 16) | (unsigned int)f2bf(a0);
    *reinterpret_cast<unsigned int*>(agg + (size_t)node * DCH + lane * 2) = o;
}

// ---------------- fused GEMM: hout = act( [agg|root] @ [Wrel;Wroot] + b ) ----------------
// M=32 rows/wave. hout may alias agg (in-place): each wave reads only its own
// 32 A-rows before its stores; no cross-wave row sharing -> no __restrict__.
__global__ void gemm_kernel(const unsigned short* agg, const unsigned short* __restrict__ root,
                            const unsigned short* __restrict__ frag, const float* __restrict__ bias,
                            unsigned short* hout, int relu) {
    int wave = threadIdx.x >> 6;
    int lane = threadIdx.x & 63;
    int quad = lane >> 4;
    int ml   = lane & 15;
    int base = blockIdx.x * 128 + wave * 32;
    int r0 = clampi(base + ml, 0, N_NODES - 1);
    int r1 = clampi(base + 16 + ml, 0, N_NODES - 1);
    v4f acc[2][8];
    #pragma unroll
    for (int h = 0; h < 2; h++)
        #pragma unroll
        for (int nt = 0; nt < 8; nt++) acc[h][nt] = (v4f){0.f, 0.f, 0.f, 0.f};
    #pragma unroll
    for (int kt = 0; kt < 8; kt++) {
        const unsigned short* asrc = (kt < 4) ? agg : root;
        int ak = (kt & 3) * 32 + quad * 8;
        v8s a0 = *reinterpret_cast<const v8s*>(asrc + (size_t)r0 * DCH + ak);
        v8s a1 = *reinterpret_cast<const v8s*>(asrc + (size_t)r1 * DCH + ak);
        #pragma unroll
        for (int nt = 0; nt < 8; nt++) {
            v8s b = *reinterpret_cast<const v8s*>(frag + (((size_t)(kt * 8 + nt)) * 64 + lane) * 8);
            acc[0][nt] = __builtin_amdgcn_mfma_f32_16x16x32_bf16(a0, b, acc[0][nt], 0, 0, 0);
            acc[1][nt] = __builtin_amdgcn_mfma_f32_16x16x32_bf16(a1, b, acc[1][nt], 0, 0, 0);
        }
    }
    #pragma unroll
    for (int h = 0; h < 2; h++) {
        int mbase = base + h * 16 + quad * 4;
        #pragma unroll
        for (int nt = 0; nt < 8; nt++) {
            int n = nt * 16 + ml;
            float bv = bias[n];
            #pragma unroll
            for (int r = 0; r < 4; r++) {
                int row = mbase + r;
                if (row < N_NODES) {
                    float v = acc[h][nt][r] + bv;
                    if (relu) v = fmaxf(v, 0.f);
                    hout[(size_t)row * DCH + n] = f2bf(v);
                }
            }
        }
    }
}

// ---------------- pooling stage 1: segmented sum into psum (batch sorted) ----------------
__global__ void __launch_bounds__(128) pool_kernel(const unsigned short* __restrict__ h,
                                                   const int* __restrict__ batch,
                                                   float* __restrict__ psum) {
    int c  = threadIdx.x; // 0..127
    int n0 = blockIdx.x * PCH;
    int n1 = n0 + PCH < N_NODES ? n0 + PCH : N_NODES;
    if (n0 >= n1) return;
    int cur = clampi(batch[n0], 0, N_GRAPHS - 1);
    float acc = 0.f;
    for (int n = n0; n < n1; n++) {
        int g = clampi(batch[n], 0, N_GRAPHS - 1);
        if (g != cur) {
            atomicAdd(&psum[cur * DCH + c], acc);
            acc = 0.f; cur = g;
        }
        acc += bf2f(h[(size_t)n * DCH + c]);
    }
    atomicAdd(&psum[cur * DCH + c], acc);
}

// ---------------- pooling stage 2: out[g] = (psum[g]/cnt_g) @ Wl + bl ----------------
static __device__ __forceinline__ int lowerb(const int* __restrict__ a, int n, int key) {
    int lo = 0, hi = n;
    while (lo < hi) { int mid = (lo + hi) >> 1; if (a[mid] < key) lo = mid + 1; else hi = mid; }
    return lo;
}

__global__ void __launch_bounds__(64) final_kernel(const float* __restrict__ psum,
                                                   const int* __restrict__ batch,
                                                   const float* __restrict__ Wl, const float* __restrict__ bl,
                                                   float* __restrict__ out) {
    __shared__ float ps[DCH];
    __shared__ int bounds[2];
    int g = blockIdx.x, tid = threadIdx.x;
    if (tid == 0) {
        bounds[0] = lowerb(batch, N_NODES, g);
        bounds[1] = lowerb(batch, N_NODES, g + 1);
    }
    __syncthreads();
    int cnt = bounds[1] - bounds[0];
    float inv = 1.0f / (float)(cnt > 1 ? cnt : 1);
    ps[tid] = psum[g * DCH + tid] * inv;
    ps[tid + 64] = psum[g * DCH + tid + 64] * inv;
    __syncthreads();
    float o = 0.f;
    #pragma unroll 4
    for (int c = 0; c < DCH; c++) o += ps[c] * Wl[c * DOUT + tid];
    out[g * DOUT + tid] = o + bl[tid];
}

extern "C" void kernel_launch(void* const* d_in, const int* in_sizes, int n_in,
                              void* d_out, int out_size, void* d_ws, size_t ws_size,
                              hipStream_t stream) {
    const float* x     = (const float*)d_in[0];
    const int*   edge  = (const int*)d_in[1];
    const int*   src   = edge;
    const int*   dst   = edge + N_EDGES;
    const int*   batch = (const int*)d_in[2];
    const float* W1rel  = (const float*)d_in[3];
    const float* b1     = (const float*)d_in[4];
    const float* W1root = (const float*)d_in[5];
    const float* W2rel  = (const float*)d_in[6];
    const float* b2     = (const float*)d_in[7];
    const float* W2root = (const float*)d_in[8];
    const float* W3rel  = (const float*)d_in[9];
    const float* b3     = (const float*)d_in[10];
    const float* W3root = (const float*)d_in[11];
    const float* Wl     = (const float*)d_in[12];
    const float* bl     = (const float*)d_in[13];
    float* out = (float*)d_out;

    char* ws = (char*)d_ws;
    size_t off = 0;
    auto carve = [&](size_t bytes) -> void* {
        void* p = ws + off;
        off += (bytes + 255) & ~(size_t)255;
        return p;
    };
    // ~58 MiB total; bucket region reuses B1 (free during CSR build)
    int*            rowptr  = (int*)carve((size_t)(N_NODES + 1) * 4);
    int*            csr     = (int*)carve((size_t)N_EDGES * 4);
    int*            gcur    = (int*)carve((size_t)PADB * 4 + (size_t)N_GRAPHS * DCH * 4); // gcur + psum, one memset
    float*          psum    = (float*)(gcur + PADB);
    unsigned short* frag    = (unsigned short*)carve((size_t)3 * 8 * 8 * 64 * 8 * 2);
    unsigned short* B1      = (unsigned short*)carve((size_t)N_NODES * DCH * 2);
    unsigned short* B2      = (unsigned short*)carve((size_t)N_NODES * DCH * 2);
    uint2*          region  = (uint2*)B1;   // 391*4608*8 = 14.4 MB <= 25.6 MB

    hipMemsetAsync(gcur, 0, (size_t)PADB * 4 + (size_t)N_GRAPHS * DCH * 4, stream);

    // CSR build: binA -> binFinish
    binA_kernel<<<(N_EDGES + CHUNK - 1) / CHUNK, 256, 0, stream>>>(src, dst, gcur, region);
    binFinish_kernel<<<NB, 256, 0, stream>>>(region, gcur, rowptr, csr);
    // features + weights
    cvt_kernel<<<(N_NODES * DCH / 4 + 255) / 256, 256, 0, stream>>>(x, B2);
    wfrag_kernel<<<(3 * 8 * 8 * 64 + 255) / 256, 256, 0, stream>>>(W1rel, W1root, W2rel, W2root, W3rel, W3root, frag);

    const int aggGrid  = (N_NODES + 3) / 4;
    const int gemmGrid = (N_NODES + 127) / 128;

    // layer 1: xb=B2; agg -> B1; gemm [B1|B2] -> B1 (relu)
    agg_kernel<<<aggGrid, 256, 0, stream>>>(B2, rowptr, csr, B1);
    gemm_kernel<<<gemmGrid, 256, 0, stream>>>(B1, B2, frag, b1, B1, 1);
    // layer 2: agg B1 -> B2; gemm [B2|B1] -> B2 (relu)
    agg_kernel<<<aggGrid, 256, 0, stream>>>(B1, rowptr, csr, B2);
    gemm_kernel<<<gemmGrid, 256, 0, stream>>>(B2, B1, frag + 32768, b2, B2, 1);
    // layer 3: agg B2 -> B1; gemm [B1|B2] -> B1 (no relu)
    agg_kernel<<<aggGrid, 256, 0, stream>>>(B2, rowptr, csr, B1);
    gemm_kernel<<<gemmGrid, 256, 0, stream>>>(B1, B2, frag + 65536, b3, B1, 0);

    // pooling: wide segmented sum, then per-graph matvec
    pool_kernel<<<(N_NODES + PCH - 1) / PCH, 128, 0, stream>>>(B1, batch, psum);
    final_kernel<<<N_GRAPHS, 64, 0, stream>>>(psum, batch, Wl, bl, out);
}